// Round 3
// baseline (835.748 us; speedup 1.0000x reference)
//
#include <hip/hip_runtime.h>
#include <stdint.h>
#include <stddef.h>

// ---------------------------------------------------------------------------
// Aligner (fp32 I/O): ex = ix@W^T+b; eo = io@W^T+b; S = ex.eo^T;
// P = softmax(S); out = P @ io.   B=8, L=2048, D=1024.
// Precision: fp32 inputs split to bf16 hi+lo; GEMMs use 3-pass split MFMA
// (hh+hl+lh) so logits are fp32-accurate to ~3e-4.  P and V in bf16 for PV.
// Workspace-adaptive chunking over batch (nb in {8,4,2,1}).
// ---------------------------------------------------------------------------

typedef short bf16x8 __attribute__((ext_vector_type(8)));   // 8 bf16 (4 VGPRs)
typedef float f32x4  __attribute__((ext_vector_type(4)));   // MFMA 16x16 accum

typedef const __attribute__((address_space(1))) uint32_t* gas_ptr;
typedef __attribute__((address_space(3))) uint32_t* las_ptr;

__device__ __forceinline__ void gl_lds16(const void* g, void* l) {
    // async global->LDS, 16B/lane; LDS dest = wave-uniform base + lane*16
    __builtin_amdgcn_global_load_lds((gas_ptr)g, (las_ptr)l, 16, 0, 0);
}

__device__ __forceinline__ unsigned short f2bf(float f) {  // RNE
    union { float f; uint32_t u; } v; v.f = f;
    uint32_t r = v.u + 0x7fffu + ((v.u >> 16) & 1u);
    return (unsigned short)(r >> 16);
}
__device__ __forceinline__ float bf2f(unsigned short h) {
    union { uint32_t u; float f; } v; v.u = ((uint32_t)h) << 16; return v.f;
}

#define L_ 2048
#define D_ 1024

// ---------------------------------------------------------------------------
// K-split: fp32 -> bf16 hi/lo.  4 elements/thread, exact grids.
// ---------------------------------------------------------------------------
__global__ __launch_bounds__(256) void k_split(
        const float* __restrict__ in, unsigned short* __restrict__ h,
        unsigned short* __restrict__ l, int n4) {
    const int i = blockIdx.x * 256 + threadIdx.x;
    if (i >= n4) return;
    float4 v = ((const float4*)in)[i];
    unsigned short h0 = f2bf(v.x), h1 = f2bf(v.y), h2 = f2bf(v.z), h3 = f2bf(v.w);
    unsigned short l0 = f2bf(v.x - bf2f(h0)), l1 = f2bf(v.y - bf2f(h1));
    unsigned short l2 = f2bf(v.z - bf2f(h2)), l3 = f2bf(v.w - bf2f(h3));
    uint2 hu, lu;
    hu.x = (uint32_t)h0 | ((uint32_t)h1 << 16);
    hu.y = (uint32_t)h2 | ((uint32_t)h3 << 16);
    lu.x = (uint32_t)l0 | ((uint32_t)l1 << 16);
    lu.y = (uint32_t)l2 | ((uint32_t)l3 << 16);
    ((uint2*)h)[i] = hu;
    ((uint2*)l)[i] = lu;
}

// ---------------------------------------------------------------------------
// K0: Vt[b][n][k] = bf16(V[b][k][n])  (V fp32), LDS-tiled 64x64.
// ---------------------------------------------------------------------------
__global__ __launch_bounds__(256) void k_transpose(
        const float* __restrict__ V, unsigned short* __restrict__ Vt) {
    __shared__ unsigned short tile[64][72];   // +8 pad
    const int b = blockIdx.z, k0 = blockIdx.x * 64, n0 = blockIdx.y * 64;
    const int t = threadIdx.x;
    const int row = t >> 2, cs = (t & 3) * 16;
    const float* src = V + ((size_t)b * L_ + k0 + row) * D_ + n0 + cs;
#pragma unroll
    for (int q = 0; q < 4; q++) {
        float4 f = ((const float4*)src)[q];
        tile[row][cs + q * 4 + 0] = f2bf(f.x);
        tile[row][cs + q * 4 + 1] = f2bf(f.y);
        tile[row][cs + q * 4 + 2] = f2bf(f.z);
        tile[row][cs + q * 4 + 3] = f2bf(f.w);
    }
    __syncthreads();
    union { unsigned short us[16]; uint4 q[2]; } pk;
#pragma unroll
    for (int j = 0; j < 16; j++) pk.us[j] = tile[cs + j][row];
    unsigned short* dst = Vt + ((size_t)b * D_ + n0 + row) * L_ + k0 + cs;
    *(uint4*)dst       = pk.q[0];
    *(uint4*)(dst + 8) = pk.q[1];
}

// ---------------------------------------------------------------------------
// K1: projection GEMM, 3-pass split.  Stacked rows [0,MROWS)=x, [MROWS,2M)=o.
// C = X@W^T + bias -> hi/lo bf16 split store.  128x128 tile, BK=32, 4 waves.
// ---------------------------------------------------------------------------
__global__ __launch_bounds__(256) void k_proj3(
        const unsigned short* __restrict__ xh, const unsigned short* __restrict__ xl,
        const unsigned short* __restrict__ oh, const unsigned short* __restrict__ ol,
        const unsigned short* __restrict__ Wh, const unsigned short* __restrict__ Wl,
        const float* __restrict__ bias,
        unsigned short* __restrict__ exh, unsigned short* __restrict__ exl,
        unsigned short* __restrict__ eoh, unsigned short* __restrict__ eol,
        int MROWS) {
    __shared__ unsigned short Ah[128 * 32], Al[128 * 32], Bh[128 * 32], Bl[128 * 32];
    const int t = threadIdx.x, lane = t & 63, wave = t >> 6;
    const int quad = lane >> 4, l16 = lane & 15;
    const int wm = (wave >> 1) * 64, wn = (wave & 1) * 64;
    const int R0 = blockIdx.x * 128;
    const int N0 = blockIdx.y * 128;
    const bool isx = (R0 < MROWS);
    const unsigned short* srcH = isx ? xh : oh;
    const unsigned short* srcL = isx ? xl : ol;
    const int r0 = isx ? R0 : (R0 - MROWS);
    unsigned short* dstH = isx ? exh : eoh;
    unsigned short* dstL = isx ? exl : eol;
    const int sr = wave * 32 + (lane >> 2);
    const int sc = (lane & 3) * 8;

    f32x4 acc[4][4];
#pragma unroll
    for (int i = 0; i < 4; i++)
#pragma unroll
        for (int j = 0; j < 4; j++) acc[i][j] = (f32x4){0.f, 0.f, 0.f, 0.f};

    for (int k0 = 0; k0 < D_; k0 += 32) {
        __syncthreads();
#pragma unroll
        for (int h = 0; h < 2; h++) {
            const size_t ra = ((size_t)(r0 + sr + h * 16)) * D_ + k0 + sc;
            const size_t rb = ((size_t)(N0 + sr + h * 16)) * D_ + k0 + sc;
            const int lo = (wave * 32 + h * 16) * 32;
            gl_lds16(srcH + ra, &Ah[lo]);
            gl_lds16(srcL + ra, &Al[lo]);
            gl_lds16(Wh + rb, &Bh[lo]);
            gl_lds16(Wl + rb, &Bl[lo]);
        }
        __syncthreads();
        bf16x8 ah[4], al[4], bh[4], bl[4];
#pragma unroll
        for (int i = 0; i < 4; i++) {
            const int o = (wm + i * 16 + l16) * 32 + quad * 8;
            ah[i] = *(const bf16x8*)&Ah[o];
            al[i] = *(const bf16x8*)&Al[o];
        }
#pragma unroll
        for (int j = 0; j < 4; j++) {
            const int o = (wn + j * 16 + l16) * 32 + quad * 8;
            bh[j] = *(const bf16x8*)&Bh[o];
            bl[j] = *(const bf16x8*)&Bl[o];
        }
#pragma unroll
        for (int i = 0; i < 4; i++)
#pragma unroll
            for (int j = 0; j < 4; j++) {
                acc[i][j] = __builtin_amdgcn_mfma_f32_16x16x32_bf16(ah[i], bh[j], acc[i][j], 0, 0, 0);
                acc[i][j] = __builtin_amdgcn_mfma_f32_16x16x32_bf16(ah[i], bl[j], acc[i][j], 0, 0, 0);
                acc[i][j] = __builtin_amdgcn_mfma_f32_16x16x32_bf16(al[i], bh[j], acc[i][j], 0, 0, 0);
            }
    }
#pragma unroll
    for (int j = 0; j < 4; j++) {
        const int n = N0 + wn + j * 16 + l16;
        const float bv = bias[n];
#pragma unroll
        for (int i = 0; i < 4; i++)
#pragma unroll
            for (int r = 0; r < 4; r++) {
                const int m = r0 + wm + i * 16 + quad * 4 + r;
                float v = acc[i][j][r] + bv;
                unsigned short h = f2bf(v);
                float lo = v - bf2f(h);
                dstH[(size_t)m * D_ + n] = h;
                dstL[(size_t)m * D_ + n] = f2bf(lo);
            }
    }
}

// ---------------------------------------------------------------------------
// K2: S[b] = (exh+exl)[b] @ (eoh+eol)[b]^T, fp32 out.  3-pass split MFMA.
// ---------------------------------------------------------------------------
__global__ __launch_bounds__(256) void k_scores(
        const unsigned short* __restrict__ exh, const unsigned short* __restrict__ exl,
        const unsigned short* __restrict__ eoh, const unsigned short* __restrict__ eol,
        float* __restrict__ S) {
    __shared__ unsigned short Ah[128 * 32], Al[128 * 32], Bh[128 * 32], Bl[128 * 32];
    const int t = threadIdx.x, lane = t & 63, wave = t >> 6;
    const int quad = lane >> 4, l16 = lane & 15;
    const int wm = (wave >> 1) * 64, wn = (wave & 1) * 64;
    const int M0 = blockIdx.x * 128, N0 = blockIdx.y * 128, b = blockIdx.z;
    const size_t rowA = (size_t)b * L_ + M0;
    const size_t rowB = (size_t)b * L_ + N0;
    const int sr = wave * 32 + (lane >> 2), sc = (lane & 3) * 8;

    f32x4 acc[4][4];
#pragma unroll
    for (int i = 0; i < 4; i++)
#pragma unroll
        for (int j = 0; j < 4; j++) acc[i][j] = (f32x4){0.f, 0.f, 0.f, 0.f};

    for (int k0 = 0; k0 < D_; k0 += 32) {
        __syncthreads();
#pragma unroll
        for (int h = 0; h < 2; h++) {
            const size_t ra = (rowA + sr + h * 16) * D_ + k0 + sc;
            const size_t rb = (rowB + sr + h * 16) * D_ + k0 + sc;
            const int lo = (wave * 32 + h * 16) * 32;
            gl_lds16(exh + ra, &Ah[lo]);
            gl_lds16(exl + ra, &Al[lo]);
            gl_lds16(eoh + rb, &Bh[lo]);
            gl_lds16(eol + rb, &Bl[lo]);
        }
        __syncthreads();
        bf16x8 ah[4], al[4], bh[4], bl[4];
#pragma unroll
        for (int i = 0; i < 4; i++) {
            const int o = (wm + i * 16 + l16) * 32 + quad * 8;
            ah[i] = *(const bf16x8*)&Ah[o];
            al[i] = *(const bf16x8*)&Al[o];
        }
#pragma unroll
        for (int j = 0; j < 4; j++) {
            const int o = (wn + j * 16 + l16) * 32 + quad * 8;
            bh[j] = *(const bf16x8*)&Bh[o];
            bl[j] = *(const bf16x8*)&Bl[o];
        }
#pragma unroll
        for (int i = 0; i < 4; i++)
#pragma unroll
            for (int j = 0; j < 4; j++) {
                acc[i][j] = __builtin_amdgcn_mfma_f32_16x16x32_bf16(ah[i], bh[j], acc[i][j], 0, 0, 0);
                acc[i][j] = __builtin_amdgcn_mfma_f32_16x16x32_bf16(ah[i], bl[j], acc[i][j], 0, 0, 0);
                acc[i][j] = __builtin_amdgcn_mfma_f32_16x16x32_bf16(al[i], bh[j], acc[i][j], 0, 0, 0);
            }
    }
#pragma unroll
    for (int i = 0; i < 4; i++)
#pragma unroll
        for (int j = 0; j < 4; j++)
#pragma unroll
            for (int r = 0; r < 4; r++) {
                const int m = wm + i * 16 + quad * 4 + r;
                const int n = N0 + wn + j * 16 + l16;
                S[(rowA + m) * L_ + n] = acc[i][j][r];
            }
}

// ---------------------------------------------------------------------------
// K3: per-row max and 1/sum(exp(s-max)) over 2048 cols.  1 block per row.
// ---------------------------------------------------------------------------
__global__ __launch_bounds__(256) void k_rowstats(
        const float* __restrict__ S, float* __restrict__ rowM, float* __restrict__ rowInvL) {
    const size_t r = blockIdx.x;
    const float* row = S + r * (size_t)L_;
    const int t = threadIdx.x, lane = t & 63, wave = t >> 6;
    float4 v0 = ((const float4*)row)[t];
    float4 v1 = ((const float4*)row)[t + 256];
    float mx = fmaxf(fmaxf(fmaxf(v0.x, v0.y), fmaxf(v0.z, v0.w)),
                     fmaxf(fmaxf(v1.x, v1.y), fmaxf(v1.z, v1.w)));
#pragma unroll
    for (int o = 32; o > 0; o >>= 1) mx = fmaxf(mx, __shfl_xor(mx, o, 64));
    __shared__ float red[4];
    __shared__ float bmax;
    if (lane == 0) red[wave] = mx;
    __syncthreads();
    if (t == 0) bmax = fmaxf(fmaxf(red[0], red[1]), fmaxf(red[2], red[3]));
    __syncthreads();
    const float m = bmax;
    float s = __expf(fminf(v0.x - m, 0.f)) + __expf(fminf(v0.y - m, 0.f))
            + __expf(fminf(v0.z - m, 0.f)) + __expf(fminf(v0.w - m, 0.f))
            + __expf(fminf(v1.x - m, 0.f)) + __expf(fminf(v1.y - m, 0.f))
            + __expf(fminf(v1.z - m, 0.f)) + __expf(fminf(v1.w - m, 0.f));
#pragma unroll
    for (int o = 32; o > 0; o >>= 1) s += __shfl_xor(s, o, 64);
    __syncthreads();
    if (lane == 0) red[wave] = s;
    __syncthreads();
    if (t == 0) {
        rowM[r] = m;
        rowInvL[r] = 1.0f / (red[0] + red[1] + red[2] + red[3]);
    }
}

// ---------------------------------------------------------------------------
// K4: out[b] = P[b] @ V[b] (fp32 out).  P on-the-fly from S (bf16), V = Vt.
// ---------------------------------------------------------------------------
__global__ __launch_bounds__(256) void k_pv(
        const float* __restrict__ S, const float* __restrict__ rowM,
        const float* __restrict__ rowInvL, const unsigned short* __restrict__ Vt,
        float* __restrict__ out) {
    __shared__ unsigned short Ps[128 * 32], Vs[128 * 32];
    const int t = threadIdx.x, lane = t & 63, wave = t >> 6;
    const int quad = lane >> 4, l16 = lane & 15;
    const int wm = (wave >> 1) * 64, wn = (wave & 1) * 64;
    const int M0 = blockIdx.x * 128, N0 = blockIdx.y * 128, b = blockIdx.z;
    const int prow = t >> 1, pcs = (t & 1) * 16;
    const size_t srow = (size_t)b * L_ + M0 + prow;
    const float rm = rowM[srow], ril = rowInvL[srow];
    const float* sptr = S + srow * (size_t)L_ + pcs;
    const int sr = wave * 32 + (lane >> 2), sc = (lane & 3) * 8;

    f32x4 acc[4][4];
#pragma unroll
    for (int i = 0; i < 4; i++)
#pragma unroll
        for (int j = 0; j < 4; j++) acc[i][j] = (f32x4){0.f, 0.f, 0.f, 0.f};

    for (int k0 = 0; k0 < L_; k0 += 32) {
        __syncthreads();
#pragma unroll
        for (int h = 0; h < 2; h++)
            gl_lds16(Vt + ((size_t)b * D_ + N0 + sr + h * 16) * L_ + k0 + sc,
                     &Vs[(wave * 32 + h * 16) * 32]);
        union { unsigned short us[16]; uint4 q[2]; } pk;
        const float4* sp = (const float4*)(sptr + k0);
#pragma unroll
        for (int qd = 0; qd < 4; qd++) {
            float4 f = sp[qd];
            pk.us[qd * 4 + 0] = f2bf(__expf(fminf(f.x - rm, 0.f)) * ril);
            pk.us[qd * 4 + 1] = f2bf(__expf(fminf(f.y - rm, 0.f)) * ril);
            pk.us[qd * 4 + 2] = f2bf(__expf(fminf(f.z - rm, 0.f)) * ril);
            pk.us[qd * 4 + 3] = f2bf(__expf(fminf(f.w - rm, 0.f)) * ril);
        }
        *(uint4*)&Ps[prow * 32 + pcs]     = pk.q[0];
        *(uint4*)&Ps[prow * 32 + pcs + 8] = pk.q[1];
        __syncthreads();
        bf16x8 a[4], bb[4];
#pragma unroll
        for (int i = 0; i < 4; i++) a[i]  = *(const bf16x8*)&Ps[(wm + i * 16 + l16) * 32 + quad * 8];
#pragma unroll
        for (int j = 0; j < 4; j++) bb[j] = *(const bf16x8*)&Vs[(wn + j * 16 + l16) * 32 + quad * 8];
#pragma unroll
        for (int i = 0; i < 4; i++)
#pragma unroll
            for (int j = 0; j < 4; j++)
                acc[i][j] = __builtin_amdgcn_mfma_f32_16x16x32_bf16(a[i], bb[j], acc[i][j], 0, 0, 0);
    }
#pragma unroll
    for (int i = 0; i < 4; i++)
#pragma unroll
        for (int j = 0; j < 4; j++)
#pragma unroll
            for (int r = 0; r < 4; r++) {
                const int m = M0 + wm + i * 16 + quad * 4 + r;
                const int n = N0 + wn + j * 16 + l16;
                out[((size_t)b * L_ + m) * D_ + n] = acc[i][j][r];
            }
}

// ---------------------------------------------------------------------------
extern "C" void kernel_launch(void* const* d_in, const int* in_sizes, int n_in,
                              void* d_out, int out_size, void* d_ws, size_t ws_size,
                              hipStream_t stream) {
    const float* ix   = (const float*)d_in[0];
    const float* io   = (const float*)d_in[1];
    const float* W    = (const float*)d_in[2];
    const float* bias = (const float*)d_in[3];
    float* out = (float*)d_out;

    const size_t MB = 1024 * 1024;
    const size_t PB_E  = (size_t)L_ * D_ * 2;    // 4 MiB: bf16 [2048,1024] per batch
    const size_t PB_S  = (size_t)L_ * L_ * 4;    // 16 MiB: fp32 [2048,2048] per batch
    const size_t PB_ST = (size_t)L_ * 4;         // 8 KiB per stats buf per batch

    // choose nb: need 4MiB (W split) + nb*(4*PB_E + 16MiB(regA) + PB_E(Vt) + 2*PB_ST)
    int nb = 8;
    while (nb > 1) {
        size_t need = 4 * MB + (size_t)nb * (4 * PB_E + PB_S + PB_E + 2 * PB_ST);
        if (need <= ws_size) break;
        nb >>= 1;
    }

    char* ws = (char*)d_ws;
    size_t off = 0;
    unsigned short* Wh = (unsigned short*)(ws + off); off += 2 * MB;
    unsigned short* Wl = (unsigned short*)(ws + off); off += 2 * MB;
    unsigned short* exh = (unsigned short*)(ws + off); off += (size_t)nb * PB_E;
    unsigned short* exl = (unsigned short*)(ws + off); off += (size_t)nb * PB_E;
    unsigned short* eoh = (unsigned short*)(ws + off); off += (size_t)nb * PB_E;
    unsigned short* eol = (unsigned short*)(ws + off); off += (size_t)nb * PB_E;
    char* regA = ws + off;                               off += (size_t)nb * PB_S;
    unsigned short* Vt = (unsigned short*)(ws + off);    off += (size_t)nb * PB_E;
    float* rowM    = (float*)(ws + off);                 off += (size_t)nb * PB_ST;
    float* rowInvL = (float*)(ws + off);
    // regA holds xh/xl/oh/ol (4 * nb*PB_E = nb*16MiB) until k_proj3 completes,
    // then is reused for S (nb*PB_S = nb*16MiB).
    unsigned short* xh = (unsigned short*)(regA);
    unsigned short* xl = (unsigned short*)(regA + (size_t)nb * PB_E);
    unsigned short* oh = (unsigned short*)(regA + (size_t)nb * PB_E * 2);
    unsigned short* ol = (unsigned short*)(regA + (size_t)nb * PB_E * 3);
    float* S = (float*)regA;

    // W split (once)
    k_split<<<1024, 256, 0, stream>>>(W, Wh, Wl, (D_ * D_) / 4);

    for (int b0 = 0; b0 < 8; b0 += nb) {
        const float* ixc = ix + (size_t)b0 * L_ * D_;
        const float* ioc = io + (size_t)b0 * L_ * D_;
        float* outc = out + (size_t)b0 * L_ * D_;
        const int nLD4 = nb * L_ * D_ / 4;

        k_split<<<nb * 2048, 256, 0, stream>>>(ixc, xh, xl, nLD4);
        k_split<<<nb * 2048, 256, 0, stream>>>(ioc, oh, ol, nLD4);
        k_transpose<<<dim3(32, 16, nb), 256, 0, stream>>>(ioc, Vt);
        k_proj3<<<dim3(32 * nb, 8), 256, 0, stream>>>(xh, xl, oh, ol, Wh, Wl, bias,
                                                      exh, exl, eoh, eol, nb * L_);
        k_scores<<<dim3(16, 16, nb), 256, 0, stream>>>(exh, exl, eoh, eol, S);
        k_rowstats<<<2048 * nb, 256, 0, stream>>>(S, rowM, rowInvL);
        k_pv<<<dim3(16, 8, nb), 256, 0, stream>>>(S, rowM, rowInvL, Vt, outc);
    }
}